// Round 17
// baseline (185.471 us; speedup 1.0000x reference)
//
#include <hip/hip_runtime.h>
#include <hip/hip_bf16.h>
#include <stdint.h>

#define BB 32
#define L1 2048
#define L2 512
#define DD 256
#define L2E 1.4426950408889634f
#define NEGS (-1.0e30f * 1.4426950408889634f)

#if __has_builtin(__builtin_amdgcn_exp2f)
#define EXP2(x) __builtin_amdgcn_exp2f(x)
#else
#define EXP2(x) exp2f(x)
#endif

typedef __attribute__((ext_vector_type(4))) float f32x4;
typedef __attribute__((ext_vector_type(8))) short bf16x8;
typedef __attribute__((ext_vector_type(4))) unsigned short u16x4;
typedef __attribute__((ext_vector_type(8))) unsigned short u16x8;

__device__ __forceinline__ unsigned short f2b(float f) {
    union { __hip_bfloat16 h; unsigned short u; } cv;
    cv.h = __float2bfloat16(f);
    return cv.u;
}

// ---- prep: fused y -> ybf (bf16 [b][j][d]), yt (bf16 [b][d][j]), sy = y@w_y ----
__global__ void prep(const float* __restrict__ y, const float* __restrict__ w_y,
                     unsigned short* __restrict__ ybf, unsigned short* __restrict__ yt,
                     float* __restrict__ sy) {
    __shared__ float tile[64][264];
    const int tid = threadIdx.x;
    const int lane = tid & 63;
    const int sub = tid >> 6;
    const int b = blockIdx.y;
    const int j0 = blockIdx.x * 64;
    const float* yb = y + ((size_t)b * L2 + j0) * DD;
    f32x4 wv = *(const f32x4*)(w_y + lane * 4);
    #pragma unroll
    for (int p = 0; p < 16; ++p) {
        int row = p * 4 + sub;
        f32x4 v = *(const f32x4*)(yb + (size_t)row * DD + lane * 4);
        *(f32x4*)&tile[row][lane * 4] = v;
        u16x4 o;
        o[0] = f2b(v[0]); o[1] = f2b(v[1]); o[2] = f2b(v[2]); o[3] = f2b(v[3]);
        *(u16x4*)(ybf + ((size_t)b * L2 + j0 + row) * DD + lane * 4) = o;
        float s = v[0]*wv[0] + v[1]*wv[1] + v[2]*wv[2] + v[3]*wv[3];
        #pragma unroll
        for (int off = 32; off; off >>= 1) s += __shfl_xor(s, off, 64);
        if (lane == 0) sy[b * L2 + j0 + row] = s;
    }
    __syncthreads();
    #pragma unroll
    for (int p = 0; p < 8; ++p) {
        int d = p * 32 + (tid >> 3);
        int jo = (tid & 7) * 8;
        u16x8 pk;
        #pragma unroll
        for (int jj = 0; jj < 8; ++jj) pk[jj] = f2b(tile[jo + jj][d]);
        *(u16x8*)(yt + ((size_t)b * DD + d) * L2 + j0 + jo) = pk;
    }
}

// ---- K1: scores+softmax (r9 verified structure), alpha -> global (swizzled bytes) ----
__launch_bounds__(512, 4)
__global__ void score_kernel(const float* __restrict__ x,
                             const unsigned short* __restrict__ ybf,
                             const float* __restrict__ sy,
                             const float* __restrict__ w_x,
                             const float* __restrict__ w_dot,
                             const float* __restrict__ bias,
                             const int* __restrict__ x_mask,
                             const int* __restrict__ y_mask,
                             unsigned short* __restrict__ alpha_g,
                             float* __restrict__ zinv_g,
                             float* __restrict__ ev_g,
                             float* __restrict__ MbA,
                             float* __restrict__ SeA) {
    __shared__ __align__(16) unsigned short big[16384]; // 32KB: xw[32][256]swz / alpha[32][512]swz
    __shared__ float sxs[32];
    __shared__ int   xms[32];
    __shared__ float pmax[8][32];
    __shared__ float pz[8][32];

    const int tid = threadIdx.x;
    const int w = tid >> 6;
    const int lane = tid & 63;
    const int g = lane >> 4, c = lane & 15;

    const int wg = blockIdx.x;
    const int slot = wg >> 3;
    const int b = (wg & 7) * 4 + (slot >> 6);
    const int rowblk = slot & 63;
    const int i0 = rowblk * 32;

    // ---- Phase A: xw bf16 -> LDS swizzled; sx folded ----
    {
        const int arow = tid >> 4;
        const int chunk = tid & 15;
        const float* xr = x + ((size_t)(b * L1 + i0 + arow)) * DD + chunk * 16;
        const float* wdp = w_dot + chunk * 16;
        const float* wxp = w_x + chunk * 16;
        float sxp = 0.f;
        #pragma unroll
        for (int it = 0; it < 4; ++it) {
            f32x4 xv = *(const f32x4*)(xr + it * 4);
            f32x4 wdv = *(const f32x4*)(wdp + it * 4);
            f32x4 wxv = *(const f32x4*)(wxp + it * 4);
            u16x4 a;
            #pragma unroll
            for (int e = 0; e < 4; ++e) a[e] = f2b(xv[e] * wdv[e]);
            sxp += xv[0]*wxv[0] + xv[1]*wxv[1] + xv[2]*wxv[2] + xv[3]*wxv[3];
            int gr = chunk * 2 + (it >> 1);
            *(u16x4*)((char*)big + arow * 512 + ((gr ^ (arow & 7)) << 4) + (it & 1) * 8) = a;
        }
        sxp += __shfl_xor(sxp, 1, 64);
        sxp += __shfl_xor(sxp, 2, 64);
        sxp += __shfl_xor(sxp, 4, 64);
        sxp += __shfl_xor(sxp, 8, 64);
        if (chunk == 0) {
            int xmv = x_mask[b * L1 + i0 + arow];
            xms[arow] = xmv;
            sxs[arow] = xmv ? NEGS : (sxp + bias[0]) * L2E;
        }
    }
    __syncthreads();                                   // B1

    // ---- Phase B: wave w owns cols [w*64,+64) for 32 rows ----
    f32x4 S[2][4];
    #pragma unroll
    for (int mt = 0; mt < 2; ++mt)
        #pragma unroll
        for (int nt = 0; nt < 4; ++nt) S[mt][nt] = (f32x4){0.f, 0.f, 0.f, 0.f};

    const unsigned short* ybase = ybf + (size_t)b * L2 * DD;
    const int col0 = w * 64;
    #pragma unroll 2
    for (int ck = 0; ck < 8; ++ck) {
        bf16x8 bfr[4];
        #pragma unroll
        for (int nt = 0; nt < 4; ++nt)
            bfr[nt] = *(const bf16x8*)(ybase + (size_t)(col0 + nt * 16 + c) * DD + ck * 32 + g * 8);
        bf16x8 afr[2];
        #pragma unroll
        for (int mt = 0; mt < 2; ++mt)
            afr[mt] = *(const bf16x8*)((char*)big + (mt * 16 + c) * 512 + ((((ck * 4 + g)) ^ (c & 7)) << 4));
        #pragma unroll
        for (int mt = 0; mt < 2; ++mt)
            #pragma unroll
            for (int nt = 0; nt < 4; ++nt)
                S[mt][nt] = __builtin_amdgcn_mfma_f32_16x16x32_bf16(afr[mt], bfr[nt], S[mt][nt], 0, 0, 0);
    }

    float syt[4];
    #pragma unroll
    for (int nt = 0; nt < 4; ++nt) {
        float sv = sy[b * L2 + col0 + nt * 16 + c];
        int ym = y_mask[b * L2 + col0 + nt * 16 + c];
        syt[nt] = ym ? NEGS : sv * L2E;
    }
    float sxr[2][4];
    #pragma unroll
    for (int mt = 0; mt < 2; ++mt)
        #pragma unroll
        for (int r = 0; r < 4; ++r)
            sxr[mt][r] = sxs[mt * 16 + 4 * g + r];
    #pragma unroll
    for (int mt = 0; mt < 2; ++mt)
        #pragma unroll
        for (int nt = 0; nt < 4; ++nt)
            #pragma unroll
            for (int r = 0; r < 4; ++r)
                S[mt][nt][r] = fmaf(S[mt][nt][r], L2E, sxr[mt][r]) + syt[nt];

    // ---- Phase C: cross-wave softmax, log2 domain ----
    #pragma unroll
    for (int mt = 0; mt < 2; ++mt)
        #pragma unroll
        for (int r = 0; r < 4; ++r) {
            float pm = S[mt][0][r];
            #pragma unroll
            for (int nt = 1; nt < 4; ++nt) pm = fmaxf(pm, S[mt][nt][r]);
            pm = fmaxf(pm, __shfl_xor(pm, 1, 64));
            pm = fmaxf(pm, __shfl_xor(pm, 2, 64));
            pm = fmaxf(pm, __shfl_xor(pm, 4, 64));
            pm = fmaxf(pm, __shfl_xor(pm, 8, 64));
            if (c == 0) pmax[w][mt * 16 + 4 * g + r] = pm;
        }
    __syncthreads();                                   // B2
    float mrow[2][4];
    #pragma unroll
    for (int mt = 0; mt < 2; ++mt)
        #pragma unroll
        for (int r = 0; r < 4; ++r) {
            int row = mt * 16 + 4 * g + r;
            float m0 = fmaxf(fmaxf(pmax[0][row], pmax[1][row]), fmaxf(pmax[2][row], pmax[3][row]));
            float m1 = fmaxf(fmaxf(pmax[4][row], pmax[5][row]), fmaxf(pmax[6][row], pmax[7][row]));
            mrow[mt][r] = fmaxf(m0, m1);
        }
    #pragma unroll
    for (int mt = 0; mt < 2; ++mt)
        #pragma unroll
        for (int r = 0; r < 4; ++r) {
            float zp = 0.f;
            #pragma unroll
            for (int nt = 0; nt < 4; ++nt) {
                float e = EXP2(S[mt][nt][r] - mrow[mt][r]);
                S[mt][nt][r] = e;
                zp += e;
            }
            zp += __shfl_xor(zp, 1, 64);
            zp += __shfl_xor(zp, 2, 64);
            zp += __shfl_xor(zp, 4, 64);
            zp += __shfl_xor(zp, 8, 64);
            if (c == 0) pz[w][mt * 16 + 4 * g + r] = zp;
        }
    __syncthreads();                                   // B3
    float zinv[2][4];
    #pragma unroll
    for (int mt = 0; mt < 2; ++mt)
        #pragma unroll
        for (int r = 0; r < 4; ++r) {
            int row = mt * 16 + 4 * g + r;
            float z0 = (pz[0][row] + pz[1][row]) + (pz[2][row] + pz[3][row]);
            float z1 = (pz[4][row] + pz[5][row]) + (pz[6][row] + pz[7][row]);
            zinv[mt][r] = 1.f / (z0 + z1);
        }

    float Mb;
    {
        float t = mrow[0][0];
        #pragma unroll
        for (int mt = 0; mt < 2; ++mt)
            #pragma unroll
            for (int r = 0; r < 4; ++r) t = fmaxf(t, mrow[mt][r]);
        t = fmaxf(t, __shfl_xor(t, 16, 64));
        t = fmaxf(t, __shfl_xor(t, 32, 64));
        Mb = t;
    }
    float ev[2][4];
    float Se = 0.f;
    #pragma unroll
    for (int mt = 0; mt < 2; ++mt)
        #pragma unroll
        for (int r = 0; r < 4; ++r) {
            ev[mt][r] = EXP2(mrow[mt][r] - Mb);
            Se += ev[mt][r];
        }
    Se += __shfl_xor(Se, 16, 64);
    Se += __shfl_xor(Se, 32, 64);
    if (tid == 0) {
        MbA[b * 64 + rowblk] = Mb;
        SeA[b * 64 + rowblk] = Se;
    }
    // per-row stats for K2 (wave 0, lanes c==0 cover all 32 rows via g,mt,r)
    if (w == 0 && c == 0) {
        #pragma unroll
        for (int mt = 0; mt < 2; ++mt)
            #pragma unroll
            for (int r = 0; r < 4; ++r) {
                int gi = b * L1 + i0 + mt * 16 + 4 * g + r;
                zinv_g[gi] = zinv[mt][r];
                ev_g[gi] = ev[mt][r];
            }
    }

    // ---- Phase D: alpha -> LDS, granule-swizzled ----
    #pragma unroll
    for (int mt = 0; mt < 2; ++mt)
        #pragma unroll
        for (int nt = 0; nt < 4; ++nt)
            #pragma unroll
            for (int r = 0; r < 4; ++r) {
                int row = mt * 16 + 4 * g + r;
                int col = col0 + nt * 16 + c;
                *(unsigned short*)((char*)big + row * 1024 +
                                   (((col >> 3) ^ (row & 7)) << 4) + (col & 7) * 2)
                    = f2b(S[mt][nt][r]);
            }
    __syncthreads();                                   // B4

    // ---- copy LDS image verbatim to global (layout preserved) ----
    unsigned short* ag = alpha_g + ((size_t)(b * L1 + i0)) * 512;
    #pragma unroll
    for (int p = 0; p < 4; ++p) {
        int t = p * 512 + tid;
        *(u16x8*)(ag + t * 8) = *(const u16x8*)(big + t * 8);
    }
}

// ---- K2: streaming PV + epilogue. No LDS; ONE barrier (alpha/out2 aliasing fence). ----
__launch_bounds__(256, 4)
__global__ void pv_kernel(const float* __restrict__ x,
                          const unsigned short* __restrict__ yt,
                          const unsigned short* __restrict__ alpha_g,
                          const float* __restrict__ zinv_g,
                          const float* __restrict__ ev_g,
                          const int* __restrict__ x_mask,
                          float* __restrict__ out0,
                          float* __restrict__ out2,
                          float* __restrict__ part) {
    const int tid = threadIdx.x;
    const int w = tid >> 6;
    const int lane = tid & 63;
    const int g = lane >> 4, c = lane & 15;

    const int wg = blockIdx.x;
    const int slot = wg >> 3;
    const int b = (wg & 7) * 4 + (slot >> 6);
    const int rowblk = slot & 63;
    const int i0 = rowblk * 32;

    const unsigned short* ytb = yt + (size_t)b * DD * L2;
    const unsigned short* ab = alpha_g + ((size_t)(b * L1 + i0)) * 512;
    const int d0 = w * 64;

    f32x4 o[2][4];
    #pragma unroll
    for (int mt = 0; mt < 2; ++mt)
        #pragma unroll
        for (int nt = 0; nt < 4; ++nt) o[mt][nt] = (f32x4){0.f, 0.f, 0.f, 0.f};

    #pragma unroll 4
    for (int kf = 0; kf < 16; ++kf) {
        bf16x8 av[2];
        #pragma unroll
        for (int mt = 0; mt < 2; ++mt)
            av[mt] = *(const bf16x8*)((const char*)ab + (mt * 16 + c) * 1024 +
                                      ((((kf * 4 + g)) ^ (c & 7)) << 4));
        bf16x8 bv[4];
        #pragma unroll
        for (int nt = 0; nt < 4; ++nt)
            bv[nt] = *(const bf16x8*)(ytb + (size_t)(d0 + nt * 16 + c) * L2 + kf * 32 + g * 8);
        #pragma unroll
        for (int mt = 0; mt < 2; ++mt)
            #pragma unroll
            for (int nt = 0; nt < 4; ++nt)
                o[mt][nt] = __builtin_amdgcn_mfma_f32_16x16x32_bf16(av[mt], bv[nt], o[mt][nt], 0, 0, 0);
    }

    // per-row stats
    float zi[2][4], ee[2][4]; int xmv[2][4];
    #pragma unroll
    for (int mt = 0; mt < 2; ++mt)
        #pragma unroll
        for (int r = 0; r < 4; ++r) {
            int gi = b * L1 + i0 + mt * 16 + 4 * g + r;
            zi[mt][r] = zinv_g[gi];
            ee[mt][r] = ev_g[gi];
            xmv[mt][r] = x_mask[gi];
        }

    // FENCE: every wave has consumed all alpha bytes of this block's 32 rows
    // before any wave overwrites them via the out2 stores below (alpha aliases
    // out2; blocks touch disjoint row slices, so cross-block is race-free).
    __syncthreads();

    const float* xb2 = x + ((size_t)b * L1 + i0) * DD;
    const size_t outb = ((size_t)b * L1 + i0) * DD;
    float eq[4] = {0.f, 0.f, 0.f, 0.f};
    #pragma unroll
    for (int mt = 0; mt < 2; ++mt)
        #pragma unroll
        for (int r = 0; r < 4; ++r) {
            int row = mt * 16 + 4 * g + r;
            #pragma unroll
            for (int nt = 0; nt < 4; ++nt) {
                int d = d0 + nt * 16 + c;
                float xv = xb2[(size_t)row * DD + d];
                float cv = xmv[mt][r] ? 0.f : o[mt][nt][r] * zi[mt][r];
                out0[outb + (size_t)row * DD + d] = cv;
                out2[outb + (size_t)row * DD + d] = xv * cv;
                eq[nt] = fmaf(ee[mt][r], xv, eq[nt]);
            }
        }
    #pragma unroll
    for (int nt = 0; nt < 4; ++nt) {
        float v = eq[nt];
        v += __shfl_xor(v, 16, 64);
        v += __shfl_xor(v, 32, 64);
        if (g == 0) part[((size_t)(b * 64 + rowblk)) * DD + d0 + nt * 16 + c] = v;
    }
}

// ---- combine: beta softmax across 64 row-blocks (log2 units) ----
__global__ void q2c_combine(const float* __restrict__ part, const float* __restrict__ MbA,
                            const float* __restrict__ SeA, float* __restrict__ out1) {
    int b = blockIdx.x, d = threadIdx.x;
    float M = -3.0e38f;
    #pragma unroll
    for (int k = 0; k < 64; ++k) M = fmaxf(M, MbA[b * 64 + k]);
    float Z = 0.f, s = 0.f;
    #pragma unroll 8
    for (int k = 0; k < 64; ++k) {
        float wk = exp2f(MbA[b * 64 + k] - M);
        Z += SeA[b * 64 + k] * wk;
        s += part[((size_t)(b * 64 + k)) * DD + d] * wk;
    }
    out1[b * DD + d] = s / Z;
}

extern "C" void kernel_launch(void* const* d_in, const int* in_sizes, int n_in,
                              void* d_out, int out_size, void* d_ws, size_t ws_size,
                              hipStream_t stream) {
    const float* x = (const float*)d_in[0];
    const float* y = (const float*)d_in[1];
    const int* x_mask = (const int*)d_in[2];
    const int* y_mask = (const int*)d_in[3];
    const float* w_x = (const float*)d_in[4];
    const float* w_y = (const float*)d_in[5];
    const float* w_dot = (const float*)d_in[6];
    const float* bias = (const float*)d_in[7];

    char* ws = (char*)d_ws;
    unsigned short* ybf = (unsigned short*)ws;              //  8,388,608 B
    unsigned short* yt  = (unsigned short*)(ws + 8388608);  //  8,388,608 B
    float* sy     = (float*)(ws + 16777216);                //     65,536 B
    float* part   = (float*)(ws + 16842752);                //  2,097,152 B
    float* MbA    = (float*)(ws + 18939904);                //      8,192 B
    float* SeA    = (float*)(ws + 18948096);                //      8,192 B
    float* zinv_g = (float*)(ws + 18956288);                //    262,144 B
    float* ev_g   = (float*)(ws + 19218432);                //    262,144 B  (~18.6 MB)

    float* out0 = (float*)d_out;                            // c2q   (B,L1,D) f32
    float* out1 = out0 + (size_t)BB * L1 * DD;              // q2c   (B,1,D)  f32
    float* out2 = out1 + (size_t)BB * DD;                   // x*c2q (B,L1,D) f32
    // alpha staged in the out2 region; K2 fences (one __syncthreads) between
    // its alpha reads and its out2 overwrites of the same rows.
    unsigned short* alpha_g = (unsigned short*)out2;

    prep<<<dim3(L2 / 64, BB), 256, 0, stream>>>(y, w_y, ybf, yt, sy);
    score_kernel<<<dim3(BB * L1 / 32), 512, 0, stream>>>(x, ybf, sy, w_x, w_dot, bias,
                                                         x_mask, y_mask, alpha_g,
                                                         zinv_g, ev_g, MbA, SeA);
    pv_kernel<<<dim3(BB * L1 / 32), 256, 0, stream>>>(x, yt, alpha_g, zinv_g, ev_g,
                                                      x_mask, out0, out2, part);
    q2c_combine<<<dim3(BB), 256, 0, stream>>>(part, MbA, SeA, out1);
}

// Round 18
// 149.193 us; speedup vs baseline: 1.2432x; 1.2432x over previous
//
#include <hip/hip_runtime.h>
#include <hip/hip_bf16.h>
#include <stdint.h>

#define BB 32
#define L1 2048
#define L2 512
#define DD 256
#define L2E 1.4426950408889634f
#define NEGS (-1.0e30f * 1.4426950408889634f)

#if __has_builtin(__builtin_amdgcn_exp2f)
#define EXP2(x) __builtin_amdgcn_exp2f(x)
#else
#define EXP2(x) exp2f(x)
#endif

typedef __attribute__((ext_vector_type(4))) float f32x4;
typedef __attribute__((ext_vector_type(8))) short bf16x8;
typedef __attribute__((ext_vector_type(4))) unsigned short u16x4;
typedef __attribute__((ext_vector_type(8))) unsigned short u16x8;

__device__ __forceinline__ unsigned short f2b(float f) {
    union { __hip_bfloat16 h; unsigned short u; } cv;
    cv.h = __float2bfloat16(f);
    return cv.u;
}

// non-temporal scalar f32 store (bypass L2 allocate): keeps y tiles L2-resident.
// asm (not __builtin_nontemporal_*: that broke the build r10/r11). Stores are
// fire-and-forget; no waitcnt needed before proceeding.
__device__ __forceinline__ void st_nt(float* p, float v) {
    asm volatile("global_store_dword %0, %1, off nt" :: "v"(p), "v"(v));
}

// ---- prep: fused y -> ybf (bf16 [b][j][d]), yt (bf16 [b][d][j]), sy = y@w_y ----
__global__ void prep(const float* __restrict__ y, const float* __restrict__ w_y,
                     unsigned short* __restrict__ ybf, unsigned short* __restrict__ yt,
                     float* __restrict__ sy) {
    __shared__ float tile[64][264];
    const int tid = threadIdx.x;
    const int lane = tid & 63;
    const int sub = tid >> 6;
    const int b = blockIdx.y;
    const int j0 = blockIdx.x * 64;
    const float* yb = y + ((size_t)b * L2 + j0) * DD;
    f32x4 wv = *(const f32x4*)(w_y + lane * 4);
    #pragma unroll
    for (int p = 0; p < 16; ++p) {
        int row = p * 4 + sub;
        f32x4 v = *(const f32x4*)(yb + (size_t)row * DD + lane * 4);
        *(f32x4*)&tile[row][lane * 4] = v;
        u16x4 o;
        o[0] = f2b(v[0]); o[1] = f2b(v[1]); o[2] = f2b(v[2]); o[3] = f2b(v[3]);
        *(u16x4*)(ybf + ((size_t)b * L2 + j0 + row) * DD + lane * 4) = o;
        float s = v[0]*wv[0] + v[1]*wv[1] + v[2]*wv[2] + v[3]*wv[3];
        #pragma unroll
        for (int off = 32; off; off >>= 1) s += __shfl_xor(s, off, 64);
        if (lane == 0) sy[b * L2 + j0 + row] = s;
    }
    __syncthreads();
    #pragma unroll
    for (int p = 0; p < 8; ++p) {
        int d = p * 32 + (tid >> 3);
        int jo = (tid & 7) * 8;
        u16x8 pk;
        #pragma unroll
        for (int jj = 0; jj < 8; ++jj) pk[jj] = f2b(tile[jo + jj][d]);
        *(u16x8*)(yt + ((size_t)b * DD + d) * L2 + j0 + jo) = pk;
    }
}

// ---- main fused kernel: r13 golden structure; ONLY change = nt output stores ----
__launch_bounds__(256, 2)
__global__ void attn_main(const float* __restrict__ x,
                          const unsigned short* __restrict__ ybf,
                          const unsigned short* __restrict__ yt,
                          const float* __restrict__ sy,
                          const float* __restrict__ w_x,
                          const float* __restrict__ w_dot,
                          const float* __restrict__ bias,
                          const int* __restrict__ x_mask,
                          const int* __restrict__ y_mask,
                          float* __restrict__ out0,
                          float* __restrict__ out2,
                          float* __restrict__ part,
                          float* __restrict__ MbA,
                          float* __restrict__ SeA) {
    __shared__ __align__(16) unsigned short big[32768];
    __shared__ float sxs[64];
    __shared__ int   xms[64];
    __shared__ float pmax[4][64];
    __shared__ float pz[4][64];

    const int tid = threadIdx.x;
    const int w = tid >> 6;
    const int lane = tid & 63;
    const int g = lane >> 4, c = lane & 15;

    const int wg = blockIdx.x;
    const int slot = wg >> 3;
    const int b = (wg & 7) * 4 + (slot >> 5);
    const int rowblk = slot & 31;
    const int i0 = rowblk * 64;

    // ---- Phase A: xw bf16 -> LDS swizzled; sx folded ----
    {
        const int arow = w * 16 + c;
        const float* xrow = x + ((size_t)(b * L1 + i0 + arow)) * DD;
        float sxpart = 0.f;
        #pragma unroll
        for (int kb = 0; kb < 8; ++kb) {
            int koff = kb * 32 + g * 8;
            f32x4 lo = *(const f32x4*)(xrow + koff);
            f32x4 hi = *(const f32x4*)(xrow + koff + 4);
            f32x4 wdlo = *(const f32x4*)(w_dot + koff);
            f32x4 wdhi = *(const f32x4*)(w_dot + koff + 4);
            f32x4 wxlo = *(const f32x4*)(w_x + koff);
            f32x4 wxhi = *(const f32x4*)(w_x + koff + 4);
            u16x8 a;
            #pragma unroll
            for (int e = 0; e < 4; ++e) {
                a[e]     = f2b(lo[e] * wdlo[e]);
                a[e + 4] = f2b(hi[e] * wdhi[e]);
                sxpart += lo[e] * wxlo[e] + hi[e] * wxhi[e];
            }
            int u = (kb * 4 + g) ^ (c & 7);
            *(u16x8*)((char*)big + arow * 512 + u * 16) = a;
        }
        sxpart += __shfl_xor(sxpart, 16, 64);
        sxpart += __shfl_xor(sxpart, 32, 64);
        if (g == 0) {
            int xmv = x_mask[b * L1 + i0 + arow];
            xms[arow] = xmv;
            sxs[arow] = xmv ? NEGS : (sxpart + bias[0]) * L2E;
        }
    }
    __syncthreads();                                   // B1

    // ---- Phase B: scores (log2-scaled), wave w owns cols [w*128, +128) ----
    f32x4 S[4][8];
    #pragma unroll
    for (int mt = 0; mt < 4; ++mt)
        #pragma unroll
        for (int nt = 0; nt < 8; ++nt) S[mt][nt] = (f32x4){0.f, 0.f, 0.f, 0.f};

    const unsigned short* ybase = ybf + (size_t)b * L2 * DD;
    const int col0 = w * 128;
    #pragma unroll 2
    for (int ck = 0; ck < 8; ++ck) {
        bf16x8 bfr[8];
        #pragma unroll
        for (int nt = 0; nt < 8; ++nt)
            bfr[nt] = *(const bf16x8*)(ybase + (size_t)(col0 + nt * 16 + c) * DD + ck * 32 + g * 8);
        bf16x8 afr[4];
        #pragma unroll
        for (int mt = 0; mt < 4; ++mt)
            afr[mt] = *(const bf16x8*)((char*)big + (mt * 16 + c) * 512 + ((((ck * 4 + g)) ^ (c & 7)) << 4));
        #pragma unroll
        for (int mt = 0; mt < 4; ++mt)
            #pragma unroll
            for (int nt = 0; nt < 8; ++nt)
                S[mt][nt] = __builtin_amdgcn_mfma_f32_16x16x32_bf16(afr[mt], bfr[nt], S[mt][nt], 0, 0, 0);
    }

    float syt[8];
    #pragma unroll
    for (int nt = 0; nt < 8; ++nt) {
        float sv = sy[b * L2 + col0 + nt * 16 + c];
        int ym = y_mask[b * L2 + col0 + nt * 16 + c];
        syt[nt] = ym ? NEGS : sv * L2E;
    }
    float sxr[4][4]; int xmr[4][4];
    #pragma unroll
    for (int mt = 0; mt < 4; ++mt)
        #pragma unroll
        for (int r = 0; r < 4; ++r) {
            sxr[mt][r] = sxs[mt * 16 + 4 * g + r];
            xmr[mt][r] = xms[mt * 16 + 4 * g + r];
        }
    #pragma unroll
    for (int mt = 0; mt < 4; ++mt)
        #pragma unroll
        for (int nt = 0; nt < 8; ++nt)
            #pragma unroll
            for (int r = 0; r < 4; ++r)
                S[mt][nt][r] = fmaf(S[mt][nt][r], L2E, sxr[mt][r]) + syt[nt];

    // ---- Phase C: cross-wave softmax (log2 domain) ----
    #pragma unroll
    for (int mt = 0; mt < 4; ++mt)
        #pragma unroll
        for (int r = 0; r < 4; ++r) {
            float pm = S[mt][0][r];
            #pragma unroll
            for (int nt = 1; nt < 8; ++nt) pm = fmaxf(pm, S[mt][nt][r]);
            pm = fmaxf(pm, __shfl_xor(pm, 1, 64));
            pm = fmaxf(pm, __shfl_xor(pm, 2, 64));
            pm = fmaxf(pm, __shfl_xor(pm, 4, 64));
            pm = fmaxf(pm, __shfl_xor(pm, 8, 64));
            if (c == 0) pmax[w][mt * 16 + 4 * g + r] = pm;
        }
    __syncthreads();                                   // B2
    float mrow[4][4];
    #pragma unroll
    for (int mt = 0; mt < 4; ++mt)
        #pragma unroll
        for (int r = 0; r < 4; ++r) {
            int row = mt * 16 + 4 * g + r;
            mrow[mt][r] = fmaxf(fmaxf(pmax[0][row], pmax[1][row]),
                                fmaxf(pmax[2][row], pmax[3][row]));
        }
    #pragma unroll
    for (int mt = 0; mt < 4; ++mt)
        #pragma unroll
        for (int r = 0; r < 4; ++r) {
            float zp = 0.f;
            #pragma unroll
            for (int nt = 0; nt < 8; ++nt) {
                float e = EXP2(S[mt][nt][r] - mrow[mt][r]);
                S[mt][nt][r] = e;
                zp += e;
            }
            zp += __shfl_xor(zp, 1, 64);
            zp += __shfl_xor(zp, 2, 64);
            zp += __shfl_xor(zp, 4, 64);
            zp += __shfl_xor(zp, 8, 64);
            if (c == 0) pz[w][mt * 16 + 4 * g + r] = zp;
        }
    __syncthreads();                                   // B3
    float zinv[4][4];
    #pragma unroll
    for (int mt = 0; mt < 4; ++mt)
        #pragma unroll
        for (int r = 0; r < 4; ++r) {
            int row = mt * 16 + 4 * g + r;
            zinv[mt][r] = 1.f / ((pz[0][row] + pz[1][row]) + (pz[2][row] + pz[3][row]));
        }

    // beta ingredients (log2 units)
    float Mb;
    {
        float t = mrow[0][0];
        #pragma unroll
        for (int mt = 0; mt < 4; ++mt)
            #pragma unroll
            for (int r = 0; r < 4; ++r) t = fmaxf(t, mrow[mt][r]);
        t = fmaxf(t, __shfl_xor(t, 16, 64));
        t = fmaxf(t, __shfl_xor(t, 32, 64));
        Mb = t;
    }
    float ev[4][4];
    float Se = 0.f;
    #pragma unroll
    for (int mt = 0; mt < 4; ++mt)
        #pragma unroll
        for (int r = 0; r < 4; ++r) {
            ev[mt][r] = EXP2(mrow[mt][r] - Mb);
            Se += ev[mt][r];
        }
    Se += __shfl_xor(Se, 16, 64);
    Se += __shfl_xor(Se, 32, 64);
    if (tid == 0) {
        MbA[b * 32 + rowblk] = Mb;
        SeA[b * 32 + rowblk] = Se;
    }

    // ---- Phase D: alpha -> LDS (overlays xw), granule-swizzled ----
    #pragma unroll
    for (int mt = 0; mt < 4; ++mt)
        #pragma unroll
        for (int nt = 0; nt < 8; ++nt)
            #pragma unroll
            for (int r = 0; r < 4; ++r) {
                int row = mt * 16 + 4 * g + r;
                int col = col0 + nt * 16 + c;
                *(unsigned short*)((char*)big + row * 1024 +
                                   (((col >> 3) ^ (row & 7)) << 4) + (col & 7) * 2)
                    = f2b(S[mt][nt][r]);
            }
    __syncthreads();                                   // B4

    // ---- Phase E: PV, wave w owns d in [w*64, +64) ----
    f32x4 o[4][4];
    #pragma unroll
    for (int mt = 0; mt < 4; ++mt)
        #pragma unroll
        for (int nt = 0; nt < 4; ++nt) o[mt][nt] = (f32x4){0.f, 0.f, 0.f, 0.f};
    const unsigned short* ytb = yt + (size_t)b * DD * L2;
    const int d0 = w * 64;
    #pragma unroll 4
    for (int kf = 0; kf < 16; ++kf) {
        bf16x8 bv[4];
        #pragma unroll
        for (int nt = 0; nt < 4; ++nt)
            bv[nt] = *(const bf16x8*)(ytb + (size_t)(d0 + nt * 16 + c) * L2 + kf * 32 + g * 8);
        bf16x8 av[4];
        #pragma unroll
        for (int mt = 0; mt < 4; ++mt)
            av[mt] = *(const bf16x8*)((char*)big + (mt * 16 + c) * 1024 + ((((kf * 4 + g)) ^ (c & 7)) << 4));
        #pragma unroll
        for (int mt = 0; mt < 4; ++mt)
            #pragma unroll
            for (int nt = 0; nt < 4; ++nt)
                o[mt][nt] = __builtin_amdgcn_mfma_f32_16x16x32_bf16(av[mt], bv[nt], o[mt][nt], 0, 0, 0);
    }

    // ---- Phase F: epilogue; out0/out2 stores NON-TEMPORAL (L2 protection) ----
    const float* xb2 = x + ((size_t)b * L1 + i0) * DD;
    const size_t outb = ((size_t)b * L1 + i0) * DD;
    float eq[4] = {0.f, 0.f, 0.f, 0.f};
    #pragma unroll
    for (int mt = 0; mt < 4; ++mt)
        #pragma unroll
        for (int r = 0; r < 4; ++r) {
            int row = mt * 16 + 4 * g + r;
            float zi = zinv[mt][r];
            float ee = ev[mt][r];
            int xmv = xmr[mt][r];
            #pragma unroll
            for (int nt = 0; nt < 4; ++nt) {
                int d = d0 + nt * 16 + c;
                float xv = xb2[(size_t)row * DD + d];
                float cv = xmv ? 0.f : o[mt][nt][r] * zi;
                st_nt(out0 + outb + (size_t)row * DD + d, cv);
                st_nt(out2 + outb + (size_t)row * DD + d, xv * cv);
                eq[nt] = fmaf(ee, xv, eq[nt]);
            }
        }
    #pragma unroll
    for (int nt = 0; nt < 4; ++nt) {
        float v = eq[nt];
        v += __shfl_xor(v, 16, 64);
        v += __shfl_xor(v, 32, 64);
        if (g == 0) part[((size_t)(b * 32 + rowblk)) * DD + d0 + nt * 16 + c] = v;
    }
}

// ---- combine: beta softmax across 32 row-blocks (log2 units) ----
__global__ void q2c_combine(const float* __restrict__ part, const float* __restrict__ MbA,
                            const float* __restrict__ SeA, float* __restrict__ out1) {
    int b = blockIdx.x, d = threadIdx.x;
    float M = -3.0e38f;
    #pragma unroll
    for (int k = 0; k < 32; ++k) M = fmaxf(M, MbA[b * 32 + k]);
    float Z = 0.f, s = 0.f;
    #pragma unroll 8
    for (int k = 0; k < 32; ++k) {
        float wk = exp2f(MbA[b * 32 + k] - M);
        Z += SeA[b * 32 + k] * wk;
        s += part[((size_t)(b * 32 + k)) * DD + d] * wk;
    }
    out1[b * DD + d] = s / Z;
}

extern "C" void kernel_launch(void* const* d_in, const int* in_sizes, int n_in,
                              void* d_out, int out_size, void* d_ws, size_t ws_size,
                              hipStream_t stream) {
    const float* x = (const float*)d_in[0];
    const float* y = (const float*)d_in[1];
    const int* x_mask = (const int*)d_in[2];
    const int* y_mask = (const int*)d_in[3];
    const float* w_x = (const float*)d_in[4];
    const float* w_y = (const float*)d_in[5];
    const float* w_dot = (const float*)d_in[6];
    const float* bias = (const float*)d_in[7];

    char* ws = (char*)d_ws;
    unsigned short* ybf = (unsigned short*)ws;              //  8,388,608 B
    unsigned short* yt  = (unsigned short*)(ws + 8388608);  //  8,388,608 B
    float* sy   = (float*)(ws + 16777216);                  //     65,536 B
    float* part = (float*)(ws + 16842752);                  //  1,048,576 B
    float* MbA  = (float*)(ws + 17891328);                  //      4,096 B
    float* SeA  = (float*)(ws + 17895424);                  //      4,096 B

    float* out0 = (float*)d_out;                            // c2q   (B,L1,D) f32
    float* out1 = out0 + (size_t)BB * L1 * DD;              // q2c   (B,1,D)  f32
    float* out2 = out1 + (size_t)BB * DD;                   // x*c2q (B,L1,D) f32

    prep<<<dim3(L2 / 64, BB), 256, 0, stream>>>(y, w_y, ybf, yt, sy);
    attn_main<<<dim3(BB * L1 / 64), 256, 0, stream>>>(x, ybf, yt, sy, w_x, w_dot, bias,
                                                      x_mask, y_mask, out0, out2,
                                                      part, MbA, SeA);
    q2c_combine<<<dim3(BB), 256, 0, stream>>>(part, MbA, SeA, out1);
}

// Round 19
// 106.620 us; speedup vs baseline: 1.7396x; 1.3993x over previous
//
#include <hip/hip_runtime.h>
#include <hip/hip_bf16.h>
#include <stdint.h>

#define BB 32
#define L1 2048
#define L2 512
#define DD 256
#define L2E 1.4426950408889634f
#define NEGS (-1.0e30f * 1.4426950408889634f)

#if __has_builtin(__builtin_amdgcn_exp2f)
#define EXP2(x) __builtin_amdgcn_exp2f(x)
#else
#define EXP2(x) exp2f(x)
#endif

typedef __attribute__((ext_vector_type(4))) float f32x4;
typedef __attribute__((ext_vector_type(8))) short bf16x8;
typedef __attribute__((ext_vector_type(4))) unsigned short u16x4;
typedef __attribute__((ext_vector_type(8))) unsigned short u16x8;

__device__ __forceinline__ unsigned short f2b(float f) {
    union { __hip_bfloat16 h; unsigned short u; } cv;
    cv.h = __float2bfloat16(f);
    return cv.u;
}

// ---- prep: y -> fragment-major bf16 tables + sy = y@w_y ----
// ybt: per (b, jtile=j/16, kchunk=k/32): 1KB block, elem (lane=g*16+c, e) = y_bf[j0+c][k0+g*8+e]
// ytt: per (b, dtile=d/16, kchunk=j/32): 1KB block, elem (lane=g*16+c, e) = y_bf[j=k0+g*8+e][d0+c]
__global__ void prep(const float* __restrict__ y, const float* __restrict__ w_y,
                     unsigned short* __restrict__ ybt, unsigned short* __restrict__ ytt,
                     float* __restrict__ sy) {
    __shared__ float tile[64][264];
    const int tid = threadIdx.x;
    const int lane = tid & 63;
    const int sub = tid >> 6;
    const int b = blockIdx.y;
    const int j0 = blockIdx.x * 64;
    const float* yb = y + ((size_t)b * L2 + j0) * DD;
    f32x4 wv = *(const f32x4*)(w_y + lane * 4);
    #pragma unroll
    for (int p = 0; p < 16; ++p) {
        int row = p * 4 + sub;
        f32x4 v = *(const f32x4*)(yb + (size_t)row * DD + lane * 4);
        *(f32x4*)&tile[row][lane * 4] = v;
        float s = v[0]*wv[0] + v[1]*wv[1] + v[2]*wv[2] + v[3]*wv[3];
        #pragma unroll
        for (int off = 32; off; off >>= 1) s += __shfl_xor(s, off, 64);
        if (lane == 0) sy[b * L2 + j0 + row] = s;
    }
    __syncthreads();
    // ybt: 4 jtiles x 8 kchunks x 64 lane-chunks = 2048 chunks of 16B
    #pragma unroll
    for (int it = 0; it < 8; ++it) {
        int idx = it * 256 + tid;
        int jt = idx >> 9;
        int rem = idx & 511;
        int kc = rem >> 6;
        int l = rem & 63;
        const float* tr = &tile[jt * 16 + (l & 15)][kc * 32 + (l >> 4) * 8];
        u16x8 pk;
        #pragma unroll
        for (int e = 0; e < 8; ++e) pk[e] = f2b(tr[e]);
        size_t off = (((size_t)b * 32 + blockIdx.x * 4 + jt) * 8 + kc) * 512 + l * 8;
        *(u16x8*)(ybt + off) = pk;
    }
    // ytt: 16 dtiles x 2 kchunks x 64 lane-chunks = 2048 chunks of 16B
    #pragma unroll
    for (int it = 0; it < 8; ++it) {
        int idx = it * 256 + tid;
        int dt = idx >> 7;
        int rem = idx & 127;
        int kk = rem >> 6;
        int l = rem & 63;
        int c = l & 15, g = l >> 4;
        u16x8 pk;
        #pragma unroll
        for (int e = 0; e < 8; ++e) pk[e] = f2b(tile[kk * 32 + g * 8 + e][dt * 16 + c]);
        size_t off = (((size_t)b * 16 + dt) * 16 + blockIdx.x * 2 + kk) * 512 + l * 8;
        *(u16x8*)(ytt + off) = pk;
    }
}

// ---- main fused kernel: r13 golden structure; y loads now fragment-major 1KB bursts ----
__launch_bounds__(256, 2)
__global__ void attn_main(const float* __restrict__ x,
                          const unsigned short* __restrict__ ybt,
                          const unsigned short* __restrict__ ytt,
                          const float* __restrict__ sy,
                          const float* __restrict__ w_x,
                          const float* __restrict__ w_dot,
                          const float* __restrict__ bias,
                          const int* __restrict__ x_mask,
                          const int* __restrict__ y_mask,
                          float* __restrict__ out0,
                          float* __restrict__ out2,
                          float* __restrict__ part,
                          float* __restrict__ MbA,
                          float* __restrict__ SeA) {
    __shared__ __align__(16) unsigned short big[32768];
    __shared__ float sxs[64];
    __shared__ int   xms[64];
    __shared__ float pmax[4][64];
    __shared__ float pz[4][64];

    const int tid = threadIdx.x;
    const int w = tid >> 6;
    const int lane = tid & 63;
    const int g = lane >> 4, c = lane & 15;

    const int wg = blockIdx.x;
    const int slot = wg >> 3;
    const int b = (wg & 7) * 4 + (slot >> 5);
    const int rowblk = slot & 31;
    const int i0 = rowblk * 64;

    // ---- Phase A: xw bf16 -> LDS swizzled; sx folded ----
    {
        const int arow = w * 16 + c;
        const float* xrow = x + ((size_t)(b * L1 + i0 + arow)) * DD;
        float sxpart = 0.f;
        #pragma unroll
        for (int kb = 0; kb < 8; ++kb) {
            int koff = kb * 32 + g * 8;
            f32x4 lo = *(const f32x4*)(xrow + koff);
            f32x4 hi = *(const f32x4*)(xrow + koff + 4);
            f32x4 wdlo = *(const f32x4*)(w_dot + koff);
            f32x4 wdhi = *(const f32x4*)(w_dot + koff + 4);
            f32x4 wxlo = *(const f32x4*)(w_x + koff);
            f32x4 wxhi = *(const f32x4*)(w_x + koff + 4);
            u16x8 a;
            #pragma unroll
            for (int e = 0; e < 4; ++e) {
                a[e]     = f2b(lo[e] * wdlo[e]);
                a[e + 4] = f2b(hi[e] * wdhi[e]);
                sxpart += lo[e] * wxlo[e] + hi[e] * wxhi[e];
            }
            int u = (kb * 4 + g) ^ (c & 7);
            *(u16x8*)((char*)big + arow * 512 + u * 16) = a;
        }
        sxpart += __shfl_xor(sxpart, 16, 64);
        sxpart += __shfl_xor(sxpart, 32, 64);
        if (g == 0) {
            int xmv = x_mask[b * L1 + i0 + arow];
            xms[arow] = xmv;
            sxs[arow] = xmv ? NEGS : (sxpart + bias[0]) * L2E;
        }
    }
    __syncthreads();                                   // B1

    // ---- Phase B: scores (log2-scaled), wave w owns cols [w*128, +128) ----
    f32x4 S[4][8];
    #pragma unroll
    for (int mt = 0; mt < 4; ++mt)
        #pragma unroll
        for (int nt = 0; nt < 8; ++nt) S[mt][nt] = (f32x4){0.f, 0.f, 0.f, 0.f};

    const unsigned short* ybt_b = ybt + (size_t)b * 131072;   // 32 jtiles * 8 kc * 512
    const int col0 = w * 128;
    #pragma unroll 2
    for (int ck = 0; ck < 8; ++ck) {
        bf16x8 bfr[8];
        #pragma unroll
        for (int nt = 0; nt < 8; ++nt)
            bfr[nt] = *(const bf16x8*)(ybt_b + ((size_t)((w * 8 + nt) * 8 + ck) * 512) + lane * 8);
        bf16x8 afr[4];
        #pragma unroll
        for (int mt = 0; mt < 4; ++mt)
            afr[mt] = *(const bf16x8*)((char*)big + (mt * 16 + c) * 512 + ((((ck * 4 + g)) ^ (c & 7)) << 4));
        #pragma unroll
        for (int mt = 0; mt < 4; ++mt)
            #pragma unroll
            for (int nt = 0; nt < 8; ++nt)
                S[mt][nt] = __builtin_amdgcn_mfma_f32_16x16x32_bf16(afr[mt], bfr[nt], S[mt][nt], 0, 0, 0);
    }

    float syt[8];
    #pragma unroll
    for (int nt = 0; nt < 8; ++nt) {
        float sv = sy[b * L2 + col0 + nt * 16 + c];
        int ym = y_mask[b * L2 + col0 + nt * 16 + c];
        syt[nt] = ym ? NEGS : sv * L2E;
    }
    float sxr[4][4]; int xmr[4][4];
    #pragma unroll
    for (int mt = 0; mt < 4; ++mt)
        #pragma unroll
        for (int r = 0; r < 4; ++r) {
            sxr[mt][r] = sxs[mt * 16 + 4 * g + r];
            xmr[mt][r] = xms[mt * 16 + 4 * g + r];
        }
    #pragma unroll
    for (int mt = 0; mt < 4; ++mt)
        #pragma unroll
        for (int nt = 0; nt < 8; ++nt)
            #pragma unroll
            for (int r = 0; r < 4; ++r)
                S[mt][nt][r] = fmaf(S[mt][nt][r], L2E, sxr[mt][r]) + syt[nt];

    // ---- Phase C: cross-wave softmax (log2 domain) ----
    #pragma unroll
    for (int mt = 0; mt < 4; ++mt)
        #pragma unroll
        for (int r = 0; r < 4; ++r) {
            float pm = S[mt][0][r];
            #pragma unroll
            for (int nt = 1; nt < 8; ++nt) pm = fmaxf(pm, S[mt][nt][r]);
            pm = fmaxf(pm, __shfl_xor(pm, 1, 64));
            pm = fmaxf(pm, __shfl_xor(pm, 2, 64));
            pm = fmaxf(pm, __shfl_xor(pm, 4, 64));
            pm = fmaxf(pm, __shfl_xor(pm, 8, 64));
            if (c == 0) pmax[w][mt * 16 + 4 * g + r] = pm;
        }
    __syncthreads();                                   // B2
    float mrow[4][4];
    #pragma unroll
    for (int mt = 0; mt < 4; ++mt)
        #pragma unroll
        for (int r = 0; r < 4; ++r) {
            int row = mt * 16 + 4 * g + r;
            mrow[mt][r] = fmaxf(fmaxf(pmax[0][row], pmax[1][row]),
                                fmaxf(pmax[2][row], pmax[3][row]));
        }
    #pragma unroll
    for (int mt = 0; mt < 4; ++mt)
        #pragma unroll
        for (int r = 0; r < 4; ++r) {
            float zp = 0.f;
            #pragma unroll
            for (int nt = 0; nt < 8; ++nt) {
                float e = EXP2(S[mt][nt][r] - mrow[mt][r]);
                S[mt][nt][r] = e;
                zp += e;
            }
            zp += __shfl_xor(zp, 1, 64);
            zp += __shfl_xor(zp, 2, 64);
            zp += __shfl_xor(zp, 4, 64);
            zp += __shfl_xor(zp, 8, 64);
            if (c == 0) pz[w][mt * 16 + 4 * g + r] = zp;
        }
    __syncthreads();                                   // B3
    float zinv[4][4];
    #pragma unroll
    for (int mt = 0; mt < 4; ++mt)
        #pragma unroll
        for (int r = 0; r < 4; ++r) {
            int row = mt * 16 + 4 * g + r;
            zinv[mt][r] = 1.f / ((pz[0][row] + pz[1][row]) + (pz[2][row] + pz[3][row]));
        }

    // beta ingredients (log2 units)
    float Mb;
    {
        float t = mrow[0][0];
        #pragma unroll
        for (int mt = 0; mt < 4; ++mt)
            #pragma unroll
            for (int r = 0; r < 4; ++r) t = fmaxf(t, mrow[mt][r]);
        t = fmaxf(t, __shfl_xor(t, 16, 64));
        t = fmaxf(t, __shfl_xor(t, 32, 64));
        Mb = t;
    }
    float ev[4][4];
    float Se = 0.f;
    #pragma unroll
    for (int mt = 0; mt < 4; ++mt)
        #pragma unroll
        for (int r = 0; r < 4; ++r) {
            ev[mt][r] = EXP2(mrow[mt][r] - Mb);
            Se += ev[mt][r];
        }
    Se += __shfl_xor(Se, 16, 64);
    Se += __shfl_xor(Se, 32, 64);
    if (tid == 0) {
        MbA[b * 32 + rowblk] = Mb;
        SeA[b * 32 + rowblk] = Se;
    }

    // ---- Phase D: alpha -> LDS (overlays xw), granule-swizzled ----
    #pragma unroll
    for (int mt = 0; mt < 4; ++mt)
        #pragma unroll
        for (int nt = 0; nt < 8; ++nt)
            #pragma unroll
            for (int r = 0; r < 4; ++r) {
                int row = mt * 16 + 4 * g + r;
                int col = col0 + nt * 16 + c;
                *(unsigned short*)((char*)big + row * 1024 +
                                   (((col >> 3) ^ (row & 7)) << 4) + (col & 7) * 2)
                    = f2b(S[mt][nt][r]);
            }
    __syncthreads();                                   // B4

    // ---- Phase E: PV, wave w owns d in [w*64, +64); ytt 1KB-burst loads ----
    f32x4 o[4][4];
    #pragma unroll
    for (int mt = 0; mt < 4; ++mt)
        #pragma unroll
        for (int nt = 0; nt < 4; ++nt) o[mt][nt] = (f32x4){0.f, 0.f, 0.f, 0.f};
    const unsigned short* ytt_b = ytt + (size_t)b * 131072;   // 16 dtiles * 16 kc * 512
    #pragma unroll 4
    for (int kf = 0; kf < 16; ++kf) {
        bf16x8 bv[4];
        #pragma unroll
        for (int nt = 0; nt < 4; ++nt)
            bv[nt] = *(const bf16x8*)(ytt_b + ((size_t)((w * 4 + nt) * 16 + kf) * 512) + lane * 8);
        bf16x8 av[4];
        #pragma unroll
        for (int mt = 0; mt < 4; ++mt)
            av[mt] = *(const bf16x8*)((char*)big + (mt * 16 + c) * 1024 + ((((kf * 4 + g)) ^ (c & 7)) << 4));
        #pragma unroll
        for (int mt = 0; mt < 4; ++mt)
            #pragma unroll
            for (int nt = 0; nt < 4; ++nt)
                o[mt][nt] = __builtin_amdgcn_mfma_f32_16x16x32_bf16(av[mt], bv[nt], o[mt][nt], 0, 0, 0);
    }

    // ---- Phase F: epilogue ----
    const float* xb2 = x + ((size_t)b * L1 + i0) * DD;
    const size_t outb = ((size_t)b * L1 + i0) * DD;
    float eq[4] = {0.f, 0.f, 0.f, 0.f};
    #pragma unroll
    for (int mt = 0; mt < 4; ++mt)
        #pragma unroll
        for (int r = 0; r < 4; ++r) {
            int row = mt * 16 + 4 * g + r;
            float zi = zinv[mt][r];
            float ee = ev[mt][r];
            int xmv = xmr[mt][r];
            #pragma unroll
            for (int nt = 0; nt < 4; ++nt) {
                int d = w * 64 + nt * 16 + c;
                float xv = xb2[(size_t)row * DD + d];
                float cv = xmv ? 0.f : o[mt][nt][r] * zi;
                out0[outb + (size_t)row * DD + d] = cv;
                out2[outb + (size_t)row * DD + d] = xv * cv;
                eq[nt] = fmaf(ee, xv, eq[nt]);
            }
        }
    #pragma unroll
    for (int nt = 0; nt < 4; ++nt) {
        float v = eq[nt];
        v += __shfl_xor(v, 16, 64);
        v += __shfl_xor(v, 32, 64);
        if (g == 0) part[((size_t)(b * 32 + rowblk)) * DD + w * 64 + nt * 16 + c] = v;
    }
}

// ---- combine: beta softmax across 32 row-blocks (log2 units) ----
__global__ void q2c_combine(const float* __restrict__ part, const float* __restrict__ MbA,
                            const float* __restrict__ SeA, float* __restrict__ out1) {
    int b = blockIdx.x, d = threadIdx.x;
    float M = -3.0e38f;
    #pragma unroll
    for (int k = 0; k < 32; ++k) M = fmaxf(M, MbA[b * 32 + k]);
    float Z = 0.f, s = 0.f;
    #pragma unroll 8
    for (int k = 0; k < 32; ++k) {
        float wk = exp2f(MbA[b * 32 + k] - M);
        Z += SeA[b * 32 + k] * wk;
        s += part[((size_t)(b * 32 + k)) * DD + d] * wk;
    }
    out1[b * DD + d] = s / Z;
}

extern "C" void kernel_launch(void* const* d_in, const int* in_sizes, int n_in,
                              void* d_out, int out_size, void* d_ws, size_t ws_size,
                              hipStream_t stream) {
    const float* x = (const float*)d_in[0];
    const float* y = (const float*)d_in[1];
    const int* x_mask = (const int*)d_in[2];
    const int* y_mask = (const int*)d_in[3];
    const float* w_x = (const float*)d_in[4];
    const float* w_y = (const float*)d_in[5];
    const float* w_dot = (const float*)d_in[6];
    const float* bias = (const float*)d_in[7];

    char* ws = (char*)d_ws;
    unsigned short* ybt = (unsigned short*)ws;              //  8,388,608 B
    unsigned short* ytt = (unsigned short*)(ws + 8388608);  //  8,388,608 B
    float* sy   = (float*)(ws + 16777216);                  //     65,536 B
    float* part = (float*)(ws + 16842752);                  //  1,048,576 B
    float* MbA  = (float*)(ws + 17891328);                  //      4,096 B
    float* SeA  = (float*)(ws + 17895424);                  //      4,096 B

    float* out0 = (float*)d_out;                            // c2q   (B,L1,D) f32
    float* out1 = out0 + (size_t)BB * L1 * DD;              // q2c   (B,1,D)  f32
    float* out2 = out1 + (size_t)BB * DD;                   // x*c2q (B,L1,D) f32

    prep<<<dim3(L2 / 64, BB), 256, 0, stream>>>(y, w_y, ybt, ytt, sy);
    attn_main<<<dim3(BB * L1 / 64), 256, 0, stream>>>(x, ybt, ytt, sy, w_x, w_dot, bias,
                                                      x_mask, y_mask, out0, out2,
                                                      part, MbA, SeA);
    q2c_combine<<<dim3(BB), 256, 0, stream>>>(part, MbA, SeA, out1);
}